// Round 4
// baseline (720.219 us; speedup 1.0000x reference)
//
#include <hip/hip_runtime.h>
#include <hip/hip_bf16.h>
#include <math.h>

// Problem constants
#define BB 2
#define CC 3
#define HH 512
#define WW 512
#define GG 64
#define LL 4096
#define FDIM 128
#define PDIM 192   // C*K*K
#define MDIM 320   // PDIM + FDIM
#define DDIM 256
#define TOPK 16
#define RHID 128
#define SCALE (1.0f/16.0f)   // 1/(sqrt(256)*TEMP)

#define NQ2 8      // queries per topk block
#define KPT 4      // keys per thread
#define CHK3 1024  // key chunk (4 keys per thread, 256 threads)
#define TOKG 16    // tokens per gemm block

// ---------------- kernel 1: copy image -> out, zero counts ----------------
__global__ void k_copy_init(const float* __restrict__ img, float* __restrict__ out,
                            int* __restrict__ counts) {
    int i = blockIdx.x * blockDim.x + threadIdx.x;
    if (i < 2 * BB) counts[i] = 0;   // qcnt[B], kcnt[B]
    int n4 = BB * CC * HH * WW / 4;
    const float4* s = (const float4*)img;
    float4* d = (float4*)out;
    for (int j = i; j < n4; j += gridDim.x * blockDim.x) d[j] = s[j];
}

// ---------------- kernel 2: build match tokens ----------------
__global__ void k_build(const float* __restrict__ img, const float* __restrict__ feat,
                        float* __restrict__ match) {
    int bl = blockIdx.x;              // 0..B*L-1
    int b = bl >> 12, l = bl & (LL - 1);
    int gy = l >> 6, gx = l & 63;
    int p = threadIdx.x;              // 0..319
    float v;
    if (p < PDIM) {
        int c = p >> 6, ky = (p >> 3) & 7, kx = p & 7;
        v = img[((b * CC + c) * HH + gy * 8 + ky) * WW + gx * 8 + kx];
    } else {
        v = feat[(b * FDIM + (p - PDIM)) * LL + l];
    }
    match[(size_t)bl * MDIM + p] = v;
}

// ---------------- kernel 3: compact masked queries AND valid keys ----------------
__global__ void k_compact(const int* __restrict__ mask, int* __restrict__ qlist,
                          int* __restrict__ klist, int* __restrict__ counts) {
    int bl = blockIdx.x * blockDim.x + threadIdx.x;
    if (bl >= BB * LL) return;
    int b = bl >> 12, l = bl & (LL - 1);
    if (mask[bl] > 0) {
        int s = atomicAdd(&counts[b], 1);          // qcnt
        qlist[b * LL + s] = l;
    } else {
        int s = atomicAdd(&counts[BB + b], 1);     // kcnt
        klist[b * LL + s] = l;
    }
}

// ---------------- kernel 4: fused token GEMM (desc + [qf|kf]) ----------------
__global__ __launch_bounds__(256) void k_gemm2(const float* __restrict__ match,
        const float* __restrict__ Wd, const float* __restrict__ Wq,
        const float* __restrict__ Wk,
        float* __restrict__ desc, float* __restrict__ qkf) {
    __shared__ float sm[TOKG * MDIM];   // 20 KB
    int base = blockIdx.x * TOKG;
    int t = threadIdx.x;
    for (int i = t; i < TOKG * MDIM; i += 256) sm[i] = match[(size_t)base * MDIM + i];
    __syncthreads();
    const float4* sm4 = (const float4*)sm;
    const float* W1p = (t < 128) ? Wq : Wk;
    int c1 = t & 127;
    float acc0[TOKG], acc1[TOKG];
#pragma unroll
    for (int tt = 0; tt < TOKG; ++tt) { acc0[tt] = 0.f; acc1[tt] = 0.f; }
    for (int m = 0; m < MDIM; m += 4) {
        float w00 = Wd[(m+0)*DDIM + t], w01 = Wd[(m+1)*DDIM + t];
        float w02 = Wd[(m+2)*DDIM + t], w03 = Wd[(m+3)*DDIM + t];
        float w10 = W1p[(m+0)*RHID + c1], w11 = W1p[(m+1)*RHID + c1];
        float w12 = W1p[(m+2)*RHID + c1], w13 = W1p[(m+3)*RHID + c1];
        int mg = m >> 2;
#pragma unroll
        for (int tt = 0; tt < TOKG; ++tt) {
            float4 s = sm4[tt * (MDIM/4) + mg];
            acc0[tt] += s.x*w00 + s.y*w01 + s.z*w02 + s.w*w03;
            acc1[tt] += s.x*w10 + s.y*w11 + s.z*w12 + s.w*w13;
        }
    }
#pragma unroll
    for (int tt = 0; tt < TOKG; ++tt) {
        desc[(size_t)(base+tt)*DDIM + t] = acc0[tt];
        qkf [(size_t)(base+tt)*DDIM + t] = acc1[tt];
    }
}

// ---------------- kernel 5: gather valid-key descriptors densely ----------------
__global__ __launch_bounds__(256) void k_gatherk(const float* __restrict__ desc,
        const int* __restrict__ klist, const int* __restrict__ counts,
        float* __restrict__ kdesc) {
    int b = blockIdx.y;
    int vcnt = counts[BB + b];
    int t = threadIdx.x;
    int row = blockIdx.x * 4 + (t >> 6);
    if (row >= vcnt) return;
    int src = klist[b * LL + row];
    int lane = t & 63;
    const float4* s = (const float4*)(desc + ((size_t)b * LL + src) * DDIM);
    float4* d = (float4*)(kdesc + ((size_t)b * LL + row) * DDIM);
    d[lane] = s[lane];
}

// ---------------- kernel 6: fused logits + wave-register top-16 (key-split) ----
__global__ __launch_bounds__(256, 4) void k_topk3(const float* __restrict__ desc,
        const float* __restrict__ kdesc,
        const int* __restrict__ qlist, const int* __restrict__ klist,
        const int* __restrict__ counts,
        float* __restrict__ tval2, int* __restrict__ tidx2) {
    int b = blockIdx.z;
    int kb = blockIdx.y;
    int cnt  = counts[b];
    int vcnt = counts[BB + b];
    int i0 = blockIdx.x * NQ2;
    if (i0 >= cnt) return;
    int nq = min(NQ2, cnt - i0);
    int t = threadIdx.x;
    int lane = t & 63, w = t >> 6;

    __shared__ float sq[NQ2 * DDIM];     // 8 KB
    __shared__ float lc[NQ2][CHK3];      // 32 KB  (total 40960 -> 4 blocks/CU)

    // stage queries (qlist read is wave-uniform per iteration)
#pragma unroll
    for (int qi = 0; qi < NQ2; ++qi) {
        int qtok = qlist[b * LL + i0 + min(qi, nq - 1)];
        sq[qi * DDIM + t] = desc[((size_t)b * LL + qtok) * DDIM + t];
    }
    __syncthreads();

    int khalf = (vcnt + 1) >> 1;
    int kstart = kb * khalf;
    int kend = min(vcnt, kstart + khalf);
    int nk = kend - kstart;

    float tva = -INFINITY, tvb = -INFINITY;
    int   tia = 0x7fffffff, tib = 0x7fffffff;

    const float4* sq4 = (const float4*)sq;
    const float4* kd4 = (const float4*)(kdesc + (size_t)b * LL * DDIM);
    const int* klb = klist + b * LL;

    int nch = (nk > 0) ? (nk + CHK3 - 1) / CHK3 : 0;
    for (int ch = 0; ch < nch; ++ch) {
        int base = kstart + ch * CHK3;
        int rr[KPT];
        bool vr[KPT];
#pragma unroll
        for (int r = 0; r < KPT; ++r) {
            int s = base + t + 256 * r;
            vr[r] = (s < kend);
            int c = min(s, vcnt - 1);
            rr[r] = (c < 0) ? 0 : c;
        }
        float acc[NQ2][KPT];
#pragma unroll
        for (int qi = 0; qi < NQ2; ++qi)
#pragma unroll
            for (int r = 0; r < KPT; ++r) acc[qi][r] = 0.f;

        float4 nx[KPT];
#pragma unroll
        for (int r = 0; r < KPT; ++r) nx[r] = kd4[(size_t)rr[r] * (DDIM/4)];
        for (int d4 = 0; d4 < DDIM/4; ++d4) {
            float4 x[KPT];
#pragma unroll
            for (int r = 0; r < KPT; ++r) x[r] = nx[r];
            if (d4 + 1 < DDIM/4) {
#pragma unroll
                for (int r = 0; r < KPT; ++r)
                    nx[r] = kd4[(size_t)rr[r] * (DDIM/4) + d4 + 1];
            }
#pragma unroll
            for (int qi = 0; qi < NQ2; ++qi) {
                float4 s = sq4[qi * (DDIM/4) + d4];
#pragma unroll
                for (int r = 0; r < KPT; ++r)
                    acc[qi][r] += s.x*x[r].x + s.y*x[r].y + s.z*x[r].z + s.w*x[r].w;
            }
        }
        __syncthreads();   // previous selection done reading lc
#pragma unroll
        for (int qi = 0; qi < NQ2; ++qi)
#pragma unroll
            for (int r = 0; r < KPT; ++r)
                lc[qi][t + 256 * r] = vr[r] ? acc[qi][r] * SCALE : -INFINITY;
        __syncthreads();

        // wave w selects for queries 2w, 2w+1; lane<16 holds sorted top-16 slot
        auto select_q = [&](float& tv, int& ti, int qi) {
            for (int j = 0; j < CHK3 / 64; ++j) {
                int p = j * 64 + lane;
                int gk = base + p;
                float v = lc[qi][p];
                int kidx = (gk < kend) ? klb[gk] : 0x7fffffff;
                float thrv = __shfl(tv, 15);
                int   thri = __shfl(ti, 15);
                bool pass = (v > thrv) || (v == thrv && kidx < thri);
                unsigned long long mball = __ballot(pass);
                while (mball) {
                    int src = __ffsll(mball) - 1;
                    float vv = __shfl(v, src);
                    int   ii = __shfl(kidx, src);
                    bool beat = (vv > tv) || (vv == tv && ii < ti);
                    float pv = __shfl_up(tv, 1);
                    int   pi = __shfl_up(ti, 1);
                    bool beatp = (lane > 0) && ((vv > pv) || (vv == pv && ii < pi));
                    if (lane < 16 && beat) { tv = beatp ? pv : vv; ti = beatp ? pi : ii; }
                    mball &= mball - 1;
                }
            }
        };
        select_q(tva, tia, 2 * w + 0);
        select_q(tvb, tib, 2 * w + 1);
    }

#pragma unroll
    for (int qq = 0; qq < 2; ++qq) {
        int qi = w * 2 + qq;
        float tv = qq ? tvb : tva;
        int   ti = qq ? tib : tia;
        if (qi < nq && lane < 16) {
            size_t o = (((size_t)b * LL + i0 + qi) * 2 + kb) * TOPK + lane;
            tval2[o] = tv;
            tidx2[o] = ti;
        }
    }
}

// ---------------- kernel 7: merge + MLP + softmax + blend + scatter ----------------
__global__ __launch_bounds__(128) void k_mlp(const float* __restrict__ match,
        const float* __restrict__ qkf,
        const float* __restrict__ tval2, const int* __restrict__ tidx2,
        const int* __restrict__ qlist, const int* __restrict__ counts,
        const float* __restrict__ W1, const float* __restrict__ b1,
        const float* __restrict__ W2, const float* __restrict__ b2,
        float* __restrict__ out) {
    int b = blockIdx.y;
    int i = blockIdx.x;
    if (i >= counts[b]) return;
    int q = qlist[b * LL + i];
    size_t slot = (size_t)b * LL + i;
    int t = threadIdx.x;

    __shared__ float mv[32];
    __shared__ int   mi[32];
    __shared__ float qfv[RHID];
    __shared__ float kfv[TOPK][RHID];
    __shared__ float tl[TOPK];
    __shared__ int   tix[TOPK];
    __shared__ float r0[TOPK], r1[TOPK];
    __shared__ float red[TOPK][2];
    __shared__ float wgt[TOPK];
    __shared__ float w2s[RHID];
    __shared__ __align__(16) float2 pkpa[RHID][18];  // 144B rows: 16B-aligned

    // ---- merge the two partial top-16 lists (exact (value desc, idx asc) rank) ----
    if (t < 32) {
        size_t o = (slot * 2 + (t >> 4)) * TOPK + (t & 15);
        mv[t] = tval2[o];
        mi[t] = tidx2[o];
    }
    __syncthreads();
    if (t < 32) {
        float v = mv[t]; int ii = mi[t];
        int rank = 0;
        for (int u = 0; u < 32; ++u) {
            float vu = mv[u]; int iu = mi[u];
            rank += ((vu > v) || (vu == v && (iu < ii || (iu == ii && u < t)))) ? 1 : 0;
        }
        if (rank < TOPK) {
            tl[rank] = v;
            int kidx = ii;
            if (kidx < 0 || kidx >= LL) kidx = 0;   // safety
            tix[rank] = kidx;
        }
    }
    __syncthreads();

    int gyq = q >> 6, gxq = q & 63;
    if (t < TOPK) {
        int kidx = tix[t];
        int gyk = kidx >> 6, gxk = kidx & 63;
        r0[t] = (float)(gyk - gyq) * (1.0f / GG);
        r1[t] = (float)(gxk - gxq) * (1.0f / GG);
    }
    qfv[t] = qkf[((size_t)b * LL + q) * DDIM + t];
    w2s[t] = W2[t];
    for (int i2 = t; i2 < TOPK * RHID; i2 += 128) {
        int kk = i2 >> 7, d = i2 & (RHID - 1);
        kfv[kk][d] = qkf[((size_t)b * LL + tix[kk]) * DDIM + RHID + d];
    }
    __syncthreads();
    {
        float qv = qfv[t];   // j = t
#pragma unroll
        for (int kk = 0; kk < TOPK; ++kk) {
            float kv = kfv[kk][t];
            pkpa[t][kk] = make_float2(qv * kv, fabsf(qv - kv));
        }
    }
    __syncthreads();

    int h = t;
    float acc[TOPK];
#pragma unroll
    for (int kk = 0; kk < TOPK; ++kk) acc[kk] = 0.f;
    for (int j = 0; j < RHID; ++j) {
        const float4* row4 = (const float4*)(&pkpa[j][0]);
        float w1a = W1[j * RHID + h];
        float w1b = W1[(RHID + j) * RHID + h];
#pragma unroll
        for (int m = 0; m < 8; ++m) {
            float4 r = row4[m];
            acc[2*m]   += r.x * w1a + r.y * w1b;
            acc[2*m+1] += r.z * w1a + r.w * w1b;
        }
    }
    float wl  = W1[256 * RHID + h];
    float wr0 = W1[257 * RHID + h];
    float wr1 = W1[258 * RHID + h];
    float bb1 = b1[h];
    float w2v = w2s[h];
    float sc[TOPK];
#pragma unroll
    for (int kk = 0; kk < TOPK; ++kk) {
        float x = acc[kk] + tl[kk] * wl + r0[kk] * wr0 + r1[kk] * wr1 + bb1;
        float g = 0.5f * x * (1.0f + erff(x * 0.70710678118654752f));
        sc[kk] = g * w2v;
    }
    int lane = t & 63, wv = t >> 6;
#pragma unroll
    for (int kk = 0; kk < TOPK; ++kk) {
        float v = sc[kk];
        for (int off = 32; off > 0; off >>= 1) v += __shfl_down(v, off);
        if (lane == 0) red[kk][wv] = v;
    }
    __syncthreads();
    if (t < TOPK) {
        float score = red[t][0] + red[t][1] + b2[0];
        float refined = tl[t] + score;
        float m = refined;
        for (int off = 8; off > 0; off >>= 1) m = fmaxf(m, __shfl_xor(m, off, 16));
        float e = expf(refined - m);
        float s = e;
        for (int off = 8; off > 0; off >>= 1) s += __shfl_xor(s, off, 16);
        wgt[t] = e / s;
    }
    __syncthreads();
    for (int p = t; p < PDIM; p += 128) {
        float o = 0.f;
#pragma unroll
        for (int kk = 0; kk < TOPK; ++kk)
            o += wgt[kk] * match[((size_t)b * LL + tix[kk]) * MDIM + p];
        int c = p >> 6, ky = (p >> 3) & 7, kx = p & 7;
        out[((b * CC + c) * HH + gyq * 8 + ky) * WW + gxq * 8 + kx] = o;
    }
}

// ---------------- launch ----------------
extern "C" void kernel_launch(void* const* d_in, const int* in_sizes, int n_in,
                              void* d_out, int out_size, void* d_ws, size_t ws_size,
                              hipStream_t stream) {
    const float* image    = (const float*)d_in[0];
    const float* features = (const float*)d_in[1];
    const int*   tmask    = (const int*)d_in[2];
    const float* W_desc   = (const float*)d_in[3];
    const float* Wq       = (const float*)d_in[4];
    const float* Wk       = (const float*)d_in[5];
    const float* W1       = (const float*)d_in[6];
    const float* b1       = (const float*)d_in[7];
    const float* W2       = (const float*)d_in[8];
    const float* b2       = (const float*)d_in[9];
    float* out = (float*)d_out;

    float* ws    = (float*)d_ws;
    float* match = ws;                                      // B*L*320
    float* desc  = match + (size_t)BB * LL * MDIM;          // B*L*256
    float* qkf   = desc  + (size_t)BB * LL * DDIM;          // B*L*256
    float* kdesc = qkf   + (size_t)BB * LL * DDIM;          // B*L*256
    float* tval2 = kdesc + (size_t)BB * LL * DDIM;          // B*L*32
    int*   tidx2 = (int*)(tval2 + (size_t)BB * LL * 2 * TOPK); // B*L*32
    int*   qlist = tidx2 + (size_t)BB * LL * 2 * TOPK;      // B*L
    int*   klist = qlist + BB * LL;                         // B*L
    int*   counts = klist + BB * LL;                        // 2*B

    k_copy_init<<<1024, 256, 0, stream>>>(image, out, counts);
    k_build<<<BB * LL, MDIM, 0, stream>>>(image, features, match);
    k_compact<<<(BB * LL + 255) / 256, 256, 0, stream>>>(tmask, qlist, klist, counts);
    k_gemm2<<<BB * LL / TOKG, 256, 0, stream>>>(match, W_desc, Wq, Wk, desc, qkf);
    k_gatherk<<<dim3(LL / 4, BB), 256, 0, stream>>>(desc, klist, counts, kdesc);
    k_topk3<<<dim3(LL / NQ2, 2, BB), 256, 0, stream>>>(desc, kdesc, qlist, klist,
                                                       counts, tval2, tidx2);
    k_mlp<<<dim3(LL, BB), 128, 0, stream>>>(match, qkf, tval2, tidx2, qlist, counts,
                                            W1, b1, W2, b2, out);
}

// Round 5
// 475.781 us; speedup vs baseline: 1.5138x; 1.5138x over previous
//
#include <hip/hip_runtime.h>
#include <hip/hip_bf16.h>
#include <math.h>

// Problem constants
#define BB 2
#define CC 3
#define HH 512
#define WW 512
#define GG 64
#define LL 4096
#define FDIM 128
#define PDIM 192   // C*K*K
#define MDIM 320   // PDIM + FDIM
#define DDIM 256
#define TOPK 16
#define RHID 128
#define SCALE (1.0f/16.0f)   // 1/(sqrt(256)*TEMP)

#define NQ2 8      // queries per topk block
#define CHK3 1024  // key chunk (4 contiguous keys per thread, 256 threads)
#define TOKG 16    // tokens per gemm block
#define TKT 32     // keys per transpose-gather block

// ---------------- kernel 1: copy image -> out, zero counts ----------------
__global__ void k_copy_init(const float* __restrict__ img, float* __restrict__ out,
                            int* __restrict__ counts) {
    int i = blockIdx.x * blockDim.x + threadIdx.x;
    if (i < 2 * BB) counts[i] = 0;   // qcnt[B], kcnt[B]
    int n4 = BB * CC * HH * WW / 4;
    const float4* s = (const float4*)img;
    float4* d = (float4*)out;
    for (int j = i; j < n4; j += gridDim.x * blockDim.x) d[j] = s[j];
}

// ---------------- kernel 2: build match tokens ----------------
__global__ void k_build(const float* __restrict__ img, const float* __restrict__ feat,
                        float* __restrict__ match) {
    int bl = blockIdx.x;              // 0..B*L-1
    int b = bl >> 12, l = bl & (LL - 1);
    int gy = l >> 6, gx = l & 63;
    int p = threadIdx.x;              // 0..319
    float v;
    if (p < PDIM) {
        int c = p >> 6, ky = (p >> 3) & 7, kx = p & 7;
        v = img[((b * CC + c) * HH + gy * 8 + ky) * WW + gx * 8 + kx];
    } else {
        v = feat[(b * FDIM + (p - PDIM)) * LL + l];
    }
    match[(size_t)bl * MDIM + p] = v;
}

// ---------------- kernel 3: compact masked queries AND valid keys ----------------
__global__ void k_compact(const int* __restrict__ mask, int* __restrict__ qlist,
                          int* __restrict__ klist, int* __restrict__ counts) {
    int bl = blockIdx.x * blockDim.x + threadIdx.x;
    if (bl >= BB * LL) return;
    int b = bl >> 12, l = bl & (LL - 1);
    if (mask[bl] > 0) {
        int s = atomicAdd(&counts[b], 1);          // qcnt
        qlist[b * LL + s] = l;
    } else {
        int s = atomicAdd(&counts[BB + b], 1);     // kcnt
        klist[b * LL + s] = l;
    }
}

// ---------------- kernel 4: fused token GEMM (desc + [qf|kf]) ----------------
__global__ __launch_bounds__(256) void k_gemm2(const float* __restrict__ match,
        const float* __restrict__ Wd, const float* __restrict__ Wq,
        const float* __restrict__ Wk,
        float* __restrict__ desc, float* __restrict__ qkf) {
    __shared__ float sm[TOKG * MDIM];   // 20 KB
    int base = blockIdx.x * TOKG;
    int t = threadIdx.x;
    for (int i = t; i < TOKG * MDIM; i += 256) sm[i] = match[(size_t)base * MDIM + i];
    __syncthreads();
    const float4* sm4 = (const float4*)sm;
    const float* W1p = (t < 128) ? Wq : Wk;
    int c1 = t & 127;
    float acc0[TOKG], acc1[TOKG];
#pragma unroll
    for (int tt = 0; tt < TOKG; ++tt) { acc0[tt] = 0.f; acc1[tt] = 0.f; }
    for (int m = 0; m < MDIM; m += 4) {
        float w00 = Wd[(m+0)*DDIM + t], w01 = Wd[(m+1)*DDIM + t];
        float w02 = Wd[(m+2)*DDIM + t], w03 = Wd[(m+3)*DDIM + t];
        float w10 = W1p[(m+0)*RHID + c1], w11 = W1p[(m+1)*RHID + c1];
        float w12 = W1p[(m+2)*RHID + c1], w13 = W1p[(m+3)*RHID + c1];
        int mg = m >> 2;
#pragma unroll
        for (int tt = 0; tt < TOKG; ++tt) {
            float4 s = sm4[tt * (MDIM/4) + mg];
            acc0[tt] += s.x*w00 + s.y*w01 + s.z*w02 + s.w*w03;
            acc1[tt] += s.x*w10 + s.y*w11 + s.z*w12 + s.w*w13;
        }
    }
#pragma unroll
    for (int tt = 0; tt < TOKG; ++tt) {
        desc[(size_t)(base+tt)*DDIM + t] = acc0[tt];
        qkf [(size_t)(base+tt)*DDIM + t] = acc1[tt];
    }
}

// ---------------- kernel 5: gather valid keys, TRANSPOSED: kdesc_t[d][kk] ----
__global__ __launch_bounds__(256) void k_gatherkT(const float* __restrict__ desc,
        const int* __restrict__ klist, const int* __restrict__ counts,
        float* __restrict__ kdesc_t) {
    int b = blockIdx.y;
    int vcnt = counts[BB + b];
    int kt = blockIdx.x * TKT;
    if (kt >= vcnt) return;
    int nk = min(TKT, vcnt - kt);
    __shared__ float sm[TKT][DDIM + 1];   // +1 pad: transpose-read conflict-free
    int t = threadIdx.x;
    // read: 4 keys per pass, one full 1KB row per wave (coalesced)
    for (int r = (t >> 6); r < nk; r += 4) {
        int src = klist[b * LL + kt + r];
        const float4* s = (const float4*)(desc + ((size_t)b * LL + src) * DDIM);
        float4 v = s[t & 63];
        int d0 = (t & 63) * 4;
        sm[r][d0] = v.x; sm[r][d0+1] = v.y; sm[r][d0+2] = v.z; sm[r][d0+3] = v.w;
    }
    __syncthreads();
    // write transposed: lanes cover 32 kk (contiguous 128B) x 2 d-rows per wave
    float* outb = kdesc_t + (size_t)b * DDIM * LL;
    int kk = t & 31;
    for (int d = (t >> 5); d < DDIM; d += 8) {
        if (kk < nk) outb[(size_t)d * LL + kt + kk] = sm[kk][d];
    }
}

// ---------------- kernel 6: fused logits + wave-register top-16 (transposed keys) ----
__global__ __launch_bounds__(256, 4) void k_topk4(const float* __restrict__ desc,
        const float* __restrict__ kdt,
        const int* __restrict__ qlist, const int* __restrict__ klist,
        const int* __restrict__ counts,
        float* __restrict__ tval2, int* __restrict__ tidx2) {
    int b = blockIdx.z;
    int kb = blockIdx.y;
    int cnt  = counts[b];
    int vcnt = counts[BB + b];
    int i0 = blockIdx.x * NQ2;
    if (i0 >= cnt) return;
    int nq = min(NQ2, cnt - i0);
    int t = threadIdx.x;
    int lane = t & 63, w = t >> 6;

    __shared__ float sq[NQ2 * DDIM];     // 8 KB
    __shared__ float lc[NQ2][CHK3];      // 32 KB  (40 KB total -> 4 blocks/CU)

#pragma unroll
    for (int qi = 0; qi < NQ2; ++qi) {
        int qtok = qlist[b * LL + i0 + min(qi, nq - 1)];
        sq[qi * DDIM + t] = desc[((size_t)b * LL + qtok) * DDIM + t];
    }
    __syncthreads();

    int khalf = (vcnt + 1) >> 1;
    int kstart = kb * khalf;
    int kend = min(vcnt, kstart + khalf);

    float tva = -INFINITY, tvb = -INFINITY;
    int   tia = 0x7fffffff, tib = 0x7fffffff;

    const float4* sq4 = (const float4*)sq;
    const float* kbase = kdt + (size_t)b * DDIM * LL;
    const int* klb = klist + b * LL;

    int nch = (kend > kstart) ? (kend - kstart + CHK3 - 1) / CHK3 : 0;
    for (int ch = 0; ch < nch; ++ch) {
        int base = kstart + ch * CHK3;
        int k0 = base + 4 * t;            // 4 contiguous keys
        int k0c = min(k0, LL - 4);        // stay inside the d-row

        float acc[NQ2][4];
#pragma unroll
        for (int qi = 0; qi < NQ2; ++qi)
#pragma unroll
            for (int r = 0; r < 4; ++r) acc[qi][r] = 0.f;

#pragma unroll 2
        for (int db = 0; db < DDIM / 4; ++db) {
            float4 qv[NQ2];
#pragma unroll
            for (int qi = 0; qi < NQ2; ++qi) qv[qi] = sq4[qi * (DDIM/4) + db];
#pragma unroll
            for (int dd = 0; dd < 4; ++dd) {
                float4 kx = *(const float4*)(kbase + (size_t)(db * 4 + dd) * LL + k0c);
#pragma unroll
                for (int qi = 0; qi < NQ2; ++qi) {
                    float sv = (dd == 0) ? qv[qi].x : (dd == 1) ? qv[qi].y
                             : (dd == 2) ? qv[qi].z : qv[qi].w;
                    acc[qi][0] += sv * kx.x;
                    acc[qi][1] += sv * kx.y;
                    acc[qi][2] += sv * kx.z;
                    acc[qi][3] += sv * kx.w;
                }
            }
        }
        __syncthreads();   // previous selection done reading lc
#pragma unroll
        for (int qi = 0; qi < NQ2; ++qi) {
            float4 o;
            o.x = (k0 + 0 < kend) ? acc[qi][0] * SCALE : -INFINITY;
            o.y = (k0 + 1 < kend) ? acc[qi][1] * SCALE : -INFINITY;
            o.z = (k0 + 2 < kend) ? acc[qi][2] * SCALE : -INFINITY;
            o.w = (k0 + 3 < kend) ? acc[qi][3] * SCALE : -INFINITY;
            *(float4*)&lc[qi][4 * t] = o;
        }
        __syncthreads();

        // wave w selects for queries 2w, 2w+1; lane<16 holds sorted top-16 slot
        auto select_q = [&](float& tv, int& ti, int qi) {
            for (int j = 0; j < CHK3 / 64; ++j) {
                int p = j * 64 + lane;
                int gk = base + p;
                float v = lc[qi][p];
                int kidx = (gk < kend) ? klb[gk] : 0x7fffffff;
                float thrv = __shfl(tv, 15);
                int   thri = __shfl(ti, 15);
                bool pass = (v > thrv) || (v == thrv && kidx < thri);
                unsigned long long mball = __ballot(pass);
                while (mball) {
                    int src = __ffsll(mball) - 1;
                    float vv = __shfl(v, src);
                    int   ii = __shfl(kidx, src);
                    bool beat = (vv > tv) || (vv == tv && ii < ti);
                    float pv = __shfl_up(tv, 1);
                    int   pi = __shfl_up(ti, 1);
                    bool beatp = (lane > 0) && ((vv > pv) || (vv == pv && ii < pi));
                    if (lane < 16 && beat) { tv = beatp ? pv : vv; ti = beatp ? pi : ii; }
                    mball &= mball - 1;
                }
            }
        };
        select_q(tva, tia, 2 * w + 0);
        select_q(tvb, tib, 2 * w + 1);
    }

#pragma unroll
    for (int qq = 0; qq < 2; ++qq) {
        int qi = w * 2 + qq;
        float tv = qq ? tvb : tva;
        int   ti = qq ? tib : tia;
        if (qi < nq && lane < 16) {
            size_t o = (((size_t)b * LL + i0 + qi) * 2 + kb) * TOPK + lane;
            tval2[o] = tv;
            tidx2[o] = ti;
        }
    }
}

// ---------------- kernel 7: merge + MLP + softmax + blend + scatter ----------------
__global__ __launch_bounds__(128) void k_mlp(const float* __restrict__ match,
        const float* __restrict__ qkf,
        const float* __restrict__ tval2, const int* __restrict__ tidx2,
        const int* __restrict__ qlist, const int* __restrict__ counts,
        const float* __restrict__ W1, const float* __restrict__ b1,
        const float* __restrict__ W2, const float* __restrict__ b2,
        float* __restrict__ out) {
    int b = blockIdx.y;
    int i = blockIdx.x;
    if (i >= counts[b]) return;
    int q = qlist[b * LL + i];
    size_t slot = (size_t)b * LL + i;
    int t = threadIdx.x;

    __shared__ float mv[32];
    __shared__ int   mi[32];
    __shared__ float qfv[RHID];
    __shared__ float kfv[TOPK][RHID];
    __shared__ float tl[TOPK];
    __shared__ int   tix[TOPK];
    __shared__ float r0[TOPK], r1[TOPK];
    __shared__ float red[TOPK][2];
    __shared__ float wgt[TOPK];
    __shared__ float w2s[RHID];
    __shared__ __align__(16) float2 pkpa[RHID][18];  // 144B rows: 16B-aligned

    // ---- merge the two partial top-16 lists (exact (value desc, idx asc) rank) ----
    if (t < 32) {
        size_t o = (slot * 2 + (t >> 4)) * TOPK + (t & 15);
        mv[t] = tval2[o];
        mi[t] = tidx2[o];
    }
    __syncthreads();
    if (t < 32) {
        float v = mv[t]; int ii = mi[t];
        int rank = 0;
        for (int u = 0; u < 32; ++u) {
            float vu = mv[u]; int iu = mi[u];
            rank += ((vu > v) || (vu == v && (iu < ii || (iu == ii && u < t)))) ? 1 : 0;
        }
        if (rank < TOPK) {
            tl[rank] = v;
            int kidx = ii;
            if (kidx < 0 || kidx >= LL) kidx = 0;   // safety
            tix[rank] = kidx;
        }
    }
    __syncthreads();

    int gyq = q >> 6, gxq = q & 63;
    if (t < TOPK) {
        int kidx = tix[t];
        int gyk = kidx >> 6, gxk = kidx & 63;
        r0[t] = (float)(gyk - gyq) * (1.0f / GG);
        r1[t] = (float)(gxk - gxq) * (1.0f / GG);
    }
    qfv[t] = qkf[((size_t)b * LL + q) * DDIM + t];
    w2s[t] = W2[t];
    for (int i2 = t; i2 < TOPK * RHID; i2 += 128) {
        int kk = i2 >> 7, d = i2 & (RHID - 1);
        kfv[kk][d] = qkf[((size_t)b * LL + tix[kk]) * DDIM + RHID + d];
    }
    __syncthreads();
    {
        float qv = qfv[t];   // j = t
#pragma unroll
        for (int kk = 0; kk < TOPK; ++kk) {
            float kv = kfv[kk][t];
            pkpa[t][kk] = make_float2(qv * kv, fabsf(qv - kv));
        }
    }
    __syncthreads();

    int h = t;
    float acc[TOPK];
#pragma unroll
    for (int kk = 0; kk < TOPK; ++kk) acc[kk] = 0.f;
    for (int j = 0; j < RHID; ++j) {
        const float4* row4 = (const float4*)(&pkpa[j][0]);
        float w1a = W1[j * RHID + h];
        float w1b = W1[(RHID + j) * RHID + h];
#pragma unroll
        for (int m = 0; m < 8; ++m) {
            float4 r = row4[m];
            acc[2*m]   += r.x * w1a + r.y * w1b;
            acc[2*m+1] += r.z * w1a + r.w * w1b;
        }
    }
    float wl  = W1[256 * RHID + h];
    float wr0 = W1[257 * RHID + h];
    float wr1 = W1[258 * RHID + h];
    float bb1 = b1[h];
    float w2v = w2s[h];
    float sc[TOPK];
#pragma unroll
    for (int kk = 0; kk < TOPK; ++kk) {
        float x = acc[kk] + tl[kk] * wl + r0[kk] * wr0 + r1[kk] * wr1 + bb1;
        float g = 0.5f * x * (1.0f + erff(x * 0.70710678118654752f));
        sc[kk] = g * w2v;
    }
    int lane = t & 63, wv = t >> 6;
#pragma unroll
    for (int kk = 0; kk < TOPK; ++kk) {
        float v = sc[kk];
        for (int off = 32; off > 0; off >>= 1) v += __shfl_down(v, off);
        if (lane == 0) red[kk][wv] = v;
    }
    __syncthreads();
    if (t < TOPK) {
        float score = red[t][0] + red[t][1] + b2[0];
        float refined = tl[t] + score;
        float m = refined;
        for (int off = 8; off > 0; off >>= 1) m = fmaxf(m, __shfl_xor(m, off, 16));
        float e = expf(refined - m);
        float s = e;
        for (int off = 8; off > 0; off >>= 1) s += __shfl_xor(s, off, 16);
        wgt[t] = e / s;
    }
    __syncthreads();
    for (int p = t; p < PDIM; p += 128) {
        float o = 0.f;
#pragma unroll
        for (int kk = 0; kk < TOPK; ++kk)
            o += wgt[kk] * match[((size_t)b * LL + tix[kk]) * MDIM + p];
        int c = p >> 6, ky = (p >> 3) & 7, kx = p & 7;
        out[((b * CC + c) * HH + gyq * 8 + ky) * WW + gxq * 8 + kx] = o;
    }
}

// ---------------- launch ----------------
extern "C" void kernel_launch(void* const* d_in, const int* in_sizes, int n_in,
                              void* d_out, int out_size, void* d_ws, size_t ws_size,
                              hipStream_t stream) {
    const float* image    = (const float*)d_in[0];
    const float* features = (const float*)d_in[1];
    const int*   tmask    = (const int*)d_in[2];
    const float* W_desc   = (const float*)d_in[3];
    const float* Wq       = (const float*)d_in[4];
    const float* Wk       = (const float*)d_in[5];
    const float* W1       = (const float*)d_in[6];
    const float* b1       = (const float*)d_in[7];
    const float* W2       = (const float*)d_in[8];
    const float* b2       = (const float*)d_in[9];
    float* out = (float*)d_out;

    float* ws    = (float*)d_ws;
    float* match = ws;                                      // B*L*320
    float* desc  = match + (size_t)BB * LL * MDIM;          // B*L*256
    float* qkf   = desc  + (size_t)BB * LL * DDIM;          // B*L*256
    float* kdt   = qkf   + (size_t)BB * LL * DDIM;          // B*256*L (transposed)
    float* tval2 = kdt   + (size_t)BB * DDIM * LL;          // B*L*32
    int*   tidx2 = (int*)(tval2 + (size_t)BB * LL * 2 * TOPK); // B*L*32
    int*   qlist = tidx2 + (size_t)BB * LL * 2 * TOPK;      // B*L
    int*   klist = qlist + BB * LL;                         // B*L
    int*   counts = klist + BB * LL;                        // 2*B

    k_copy_init<<<1024, 256, 0, stream>>>(image, out, counts);
    k_build<<<BB * LL, MDIM, 0, stream>>>(image, features, match);
    k_compact<<<(BB * LL + 255) / 256, 256, 0, stream>>>(tmask, qlist, klist, counts);
    k_gemm2<<<BB * LL / TOKG, 256, 0, stream>>>(match, W_desc, Wq, Wk, desc, qkf);
    k_gatherkT<<<dim3(LL / TKT, BB), 256, 0, stream>>>(desc, klist, counts, kdt);
    k_topk4<<<dim3(LL / NQ2, 2, BB), 256, 0, stream>>>(desc, kdt, qlist, klist,
                                                       counts, tval2, tidx2);
    k_mlp<<<dim3(LL, BB), 128, 0, stream>>>(match, qkf, tval2, tidx2, qlist, counts,
                                            W1, b1, W2, b2, out);
}